// Round 8
// baseline (104.440 us; speedup 1.0000x reference)
//
#include <hip/hip_runtime.h>
#include <hip/hip_bf16.h>
#include <math.h>

// ---------------------------------------------------------------------------
// MMD loss:  mmd = 2*Sxx_upper/(n(n-1)) + 2*Syy_upper/(m(m-1)) - 2*Sxy/(n*m)
// k(a,b) = exp(-|a-b|^2 / 128)  (sigma^2 = D = 64), N = M = 8192, D = 64.
//
// Algebra: store A' = A * sqrt(log2e)/8 in bf16 and s = 0.5*|a'|^2 (f32).
// Then  exp(-|a-b|^2/128) = exp2( dot(a',b') - s_a - s_b ).
// MFMA C-init = nsx + nsy (register-resident, prologue-loaded).
//
// Hard-won structure lessons (R0..R7):
//  - default __launch_bounds__(256) ONLY. (256,8) -> compiler spills (373us).
//  - runtime `sym` + in-loop guards keep regs in check (R1: 108 VGPR, 2x).
//  - NO single-address atomic finalize (~65us serialized tail, R1/R4).
//  - compact balance-ordered grid + prologue-hoisted norms (R6, 79->56us).
//  - B panel in LDS, XOR-swizzle f(x)=x^(((x>>7)&7)<<4) BOTH sides (R7,
//    56->~40us, 0 bank conflicts).
//  - R8: TLP is the latency-hider -> LDS was the occupancy cap (33KB = 4
//    blocks/CU). Tile 128x128 (16KB panel) -> 8 blocks/CU, 2x residency.
//    4-way accumulator split breaks the serial add chain.
// ---------------------------------------------------------------------------

using short8  = __attribute__((ext_vector_type(8))) short;  // 8 bf16 (4 VGPRs)
using f32x4   = __attribute__((ext_vector_type(4))) float;  // 4 fp32
using float4v = __attribute__((ext_vector_type(4))) float;

#define NROWS 8192
#define DDIM  64
// Active blocks only: 4096 XY (dispatched first) + 2*2080 sym-upper(128x128).
#define GRID_MAIN (4096 + 2 * 2080)

// sqrt(log2(e)) / 8
#define PRESCALE 0.15014030109830622f

__device__ __forceinline__ float exp2_fast(float x) {
#if __has_builtin(__builtin_amdgcn_exp2f)
    return __builtin_amdgcn_exp2f(x);
#else
    return exp2f(x);
#endif
}

// ---------------------------------------------------------------------------
// Prep: normalize X, prescale, cast X/Y to bf16, compute s = 0.5*|row'|^2
// from the bf16-rounded values. 4 rows per wave, float4 loads. (R6-proven.)
// ---------------------------------------------------------------------------
__global__ __launch_bounds__(256) void mmd_prep(
    const float* __restrict__ z_seq, const float* __restrict__ pmean,
    const float* __restrict__ pstd, const float* __restrict__ z_prior,
    __hip_bfloat16* __restrict__ Xb, __hip_bfloat16* __restrict__ Yb,
    float* __restrict__ sxx, float* __restrict__ syy)
{
    const int tid  = threadIdx.x;
    const int lane = tid & 63;
    const int wid  = tid >> 6;
    const int w    = blockIdx.x * 4 + wid;       // wave id, 0..4095
    const int sub  = lane >> 4;                  // row within wave, 0..3
    const int row  = w * 4 + sub;                // 0..16383
    const int d0   = (lane & 15) * 4;            // dim offset, 0..60

    float4v v;
    __hip_bfloat16* dst;
    float* sdst;
    int r;
    if (row < NROWS) {
        r = row;
        float4v z  = *reinterpret_cast<const float4v*>(z_seq + (size_t)r * DDIM + d0);
        float4v pm = *reinterpret_cast<const float4v*>(pmean + d0);
        float4v ps = *reinterpret_cast<const float4v*>(pstd + d0);
#pragma unroll
        for (int k = 0; k < 4; ++k) v[k] = (z[k] - pm[k]) / ps[k];
        dst = Xb; sdst = sxx;
    } else {
        r = row - NROWS;
        v = *reinterpret_cast<const float4v*>(z_prior + (size_t)r * DDIM + d0);
        dst = Yb; sdst = syy;
    }

    ushort4 hb;
    float sq = 0.0f;
#pragma unroll
    for (int k = 0; k < 4; ++k) {
        __hip_bfloat16 b = __float2bfloat16(v[k] * PRESCALE);
        reinterpret_cast<__hip_bfloat16*>(&hb)[k] = b;
        float vb = __bfloat162float(b);
        sq += vb * vb;
    }
    *reinterpret_cast<ushort4*>(dst + (size_t)r * DDIM + d0) = hb;

    // reduce across the 16 lanes of this row-group (xor<16 stays in group)
#pragma unroll
    for (int off = 8; off; off >>= 1) sq += __shfl_xor(sq, off, 64);
    if ((lane & 15) == 0) sdst[r] = 0.5f * sq;
}

// ---------------------------------------------------------------------------
// Main: compact 1-D grid of ACTIVE blocks only.  Block tile 128(i) x 128(j),
// 4 waves, wave tile 32(i) x 128(j).
//   bid <  4096 : XY block, bi = bid>>6 (0..63), bj = bid&63.
//   bid >= 4096 : t = bid-4096; sym mode = t&1 (0:XX, 1:YY);
//                 u = t>>1 in [0,2080): bj = tri-decode, bi = u - bj(bj+1)/2,
//                 bi <= bj (upper incl. diagonal).
// B panel (128x64 bf16 = 16KB) staged to LDS once, XOR-swizzled both sides;
// inner loop is ds_read_b128 + MFMA + exp2 only.
// ---------------------------------------------------------------------------
__global__ __launch_bounds__(256) void mmd_main(
    const __hip_bfloat16* __restrict__ Xb, const __hip_bfloat16* __restrict__ Yb,
    const float* __restrict__ sxx, const float* __restrict__ syy,
    double* __restrict__ partials)
{
    __shared__ __align__(16) char Bs[16384];     // 128 cols x 128 B

    const int bid = blockIdx.x;

    int bi, bj;
    bool sym;
    const __hip_bfloat16* A;
    const __hip_bfloat16* Bp;
    const float* sa;
    const float* sb;

    if (bid < 4096) {                       // XY: heavy, uniform, FIRST
        sym = false;
        bi = bid >> 6; bj = bid & 63;
        A = Xb; Bp = Yb; sa = sxx; sb = syy;
    } else {                                // sym upper-triangle blocks
        sym = true;
        const int t = bid - 4096;
        const int u = t >> 1;
        int b = (int)((sqrtf((float)(8 * u + 1)) - 1.0f) * 0.5f);
        while ((b + 1) * (b + 2) / 2 <= u) ++b;  // integer fixup of float sqrt
        while (b * (b + 1) / 2 > u) --b;
        bj = b;
        bi = u - b * (b + 1) / 2;           // 0..bj  (upper incl. diagonal)
        if (t & 1) { A = Yb; Bp = Yb; sa = syy; sb = syy; }
        else       { A = Xb; Bp = Xb; sa = sxx; sb = sxx; }
    }

    const int tid  = threadIdx.x;
    const int lane = tid & 63;
    const int wid  = tid >> 6;
    const int quad = lane >> 4;
    const int l15  = lane & 15;

    const int iBlock = bi * 128;
    const int jBlock = bj * 128;

    // ---- Stage B panel -> LDS, source pre-swizzled with f(x)=x^(((x>>7)&7)<<4)
    // so a swizzled read is conflict-free.  16 chunks of 1024B, 4 per wave.
    {
        const char* gB = (const char*)Bp + (size_t)jBlock * 128;
#pragma unroll
        for (int k = 0; k < 4; ++k) {
            const int c  = wid * 4 + k;
            const int x  = c * 1024 + lane * 16;
            const int gx = x ^ (((x >> 7) & 7) << 4);
            __builtin_amdgcn_global_load_lds(
                (const __attribute__((address_space(1))) void*)(gB + gx),
                (__attribute__((address_space(3))) void*)(Bs + c * 1024),
                16, 0, 0);
        }
    }

    const int i0 = iBlock + wid * 32;          // wave row origin (32 rows)

    // Persistent A fragments + negated row half-norms (overlap LDS staging).
    short8 af[2][2];
    f32x4  nsx[2];
#pragma unroll
    for (int mt = 0; mt < 2; ++mt) {
        const int ar = i0 + mt * 16 + l15;
#pragma unroll
        for (int ks = 0; ks < 2; ++ks)
            af[mt][ks] = *reinterpret_cast<const short8*>(
                A + (size_t)ar * DDIM + ks * 32 + quad * 8);
        f32x4 s4 = *reinterpret_cast<const f32x4*>(sa + i0 + mt * 16 + quad * 4);
        nsx[mt] = -s4;
    }

    // Hoisted negated column half-norms for this lane's 8 j-tiles.
    float nsy[8];
#pragma unroll
    for (int nt = 0; nt < 8; ++nt) nsy[nt] = -sb[jBlock + l15 + nt * 16];

    __syncthreads();   // staging complete (compiler drains vmcnt first)

    // Per-lane constant swizzle for reads: col&7 == l15&7 (col = 16nt+l15).
    const int swz   = (l15 & 7) << 4;
    const int off0  = (quad * 16) ^ swz;          // ks=0 in-col byte offset
    const int off1  = (quad * 16 + 64) ^ swz;     // ks=1 in-col byte offset
    const char* lb0 = Bs + l15 * 128;

    // 4 accumulators (one per C row) break the serial add chain.
    float ls0 = 0.0f, ls1 = 0.0f, ls2 = 0.0f, ls3 = 0.0f;

#pragma unroll
    for (int nt = 0; nt < 8; ++nt) {
        const int jt = jBlock + nt * 16;
        if (sym && jt < i0) continue;    // both mt-tiles below diagonal

        const char* lp = lb0 + nt * 16 * 128;
        short8 b0 = *reinterpret_cast<const short8*>(lp + off0);
        short8 b1 = *reinterpret_cast<const short8*>(lp + off1);

#pragma unroll
        for (int mt = 0; mt < 2; ++mt) {
            const int it = i0 + mt * 16;
            if (sym && jt < it) continue;      // tile strictly below diag

            f32x4 acc4;
#pragma unroll
            for (int r = 0; r < 4; ++r) acc4[r] = nsx[mt][r] + nsy[nt];
            acc4 = __builtin_amdgcn_mfma_f32_16x16x32_bf16(af[mt][0], b0, acc4, 0, 0, 0);
            acc4 = __builtin_amdgcn_mfma_f32_16x16x32_bf16(af[mt][1], b1, acc4, 0, 0, 0);

            if (sym && jt == it) {
                // diagonal tile: count only j > i (trace excluded exactly)
                ls0 += (l15 > quad * 4 + 0) ? exp2_fast(acc4[0]) : 0.0f;
                ls1 += (l15 > quad * 4 + 1) ? exp2_fast(acc4[1]) : 0.0f;
                ls2 += (l15 > quad * 4 + 2) ? exp2_fast(acc4[2]) : 0.0f;
                ls3 += (l15 > quad * 4 + 3) ? exp2_fast(acc4[3]) : 0.0f;
            } else {
                ls0 += exp2_fast(acc4[0]);
                ls1 += exp2_fast(acc4[1]);
                ls2 += exp2_fast(acc4[2]);
                ls3 += exp2_fast(acc4[3]);
            }
        }
    }

    float lsum = (ls0 + ls1) + (ls2 + ls3);

    // wave reduce
#pragma unroll
    for (int off = 32; off; off >>= 1) lsum += __shfl_xor(lsum, off, 64);

    __shared__ float ws4[4];
    if (lane == 0) ws4[wid] = lsum;
    __syncthreads();
    if (tid == 0) {
        double tot = (double)ws4[0] + (double)ws4[1] + (double)ws4[2] + (double)ws4[3];
        partials[bid] = tot;
    }
}

// ---------------------------------------------------------------------------
// Finalize: reduce GRID_MAIN block partials with per-mode coefficients.
// bid < 4096 -> XY (negative coeff); else sym (x2 folds sum_{i!=j}).
// ---------------------------------------------------------------------------
__global__ __launch_bounds__(256) void mmd_final(
    const double* __restrict__ partials, float* __restrict__ out)
{
    const int tid = threadIdx.x;
    const double cs = 2.0 / (8192.0 * 8191.0);       // sym modes
    const double cx = -2.0 / (8192.0 * 8192.0);      // XY

    double s = 0.0;
    for (int idx = tid; idx < GRID_MAIN; idx += 256) {
        double c = (idx < 4096) ? cx : cs;
        s += partials[idx] * c;
    }
#pragma unroll
    for (int off = 32; off; off >>= 1) s += __shfl_xor(s, off, 64);

    __shared__ double wsum[4];
    const int lane = tid & 63, wid = tid >> 6;
    if (lane == 0) wsum[wid] = s;
    __syncthreads();
    if (tid == 0) {
        double mmd = wsum[0] + wsum[1] + wsum[2] + wsum[3];
        out[0] = (float)(mmd > 0.0 ? mmd : 0.0);
    }
}

// ---------------------------------------------------------------------------
extern "C" void kernel_launch(void* const* d_in, const int* in_sizes, int n_in,
                              void* d_out, int out_size, void* d_ws, size_t ws_size,
                              hipStream_t stream) {
    const float* z_seq   = (const float*)d_in[0];   // [16,512,64]
    const float* pmean   = (const float*)d_in[1];   // [64]
    const float* pstd    = (const float*)d_in[2];   // [64]
    const float* z_prior = (const float*)d_in[3];   // [8192,64]
    float* out = (float*)d_out;

    char* ws = (char*)d_ws;
    __hip_bfloat16* Xb = (__hip_bfloat16*)(ws);                    // 1 MB
    __hip_bfloat16* Yb = (__hip_bfloat16*)(ws + (1u << 20));       // 1 MB
    float* sxx = (float*)(ws + (2u << 20));                        // 32 KB
    float* syy = (float*)(ws + (2u << 20) + 32768);                // 32 KB
    double* partials = (double*)(ws + (2u << 20) + 65536);         // ~65 KB

    mmd_prep<<<dim3(1024), dim3(256), 0, stream>>>(
        z_seq, pmean, pstd, z_prior, Xb, Yb, sxx, syy);
    mmd_main<<<dim3(GRID_MAIN), dim3(256), 0, stream>>>(
        Xb, Yb, sxx, syy, partials);
    mmd_final<<<dim3(1), dim3(256), 0, stream>>>(partials, out);
}

// Round 9
// 100.823 us; speedup vs baseline: 1.0359x; 1.0359x over previous
//
#include <hip/hip_runtime.h>
#include <hip/hip_bf16.h>
#include <math.h>

// ---------------------------------------------------------------------------
// MMD loss:  mmd = 2*Sxx_upper/(n(n-1)) + 2*Syy_upper/(m(m-1)) - 2*Sxy/(n*m)
// k(a,b) = exp(-|a-b|^2 / 128)  (sigma^2 = D = 64), N = M = 8192, D = 64.
//
// Algebra: store A' = A * sqrt(log2e)/8 in bf16 and s = 0.5*|a'|^2 (f32).
// Then  exp(-|a-b|^2/128) = exp2( dot(a',b') - s_a - s_b ).
// MFMA C-init = nsx + nsy (register-resident, prologue-loaded).
//
// Hard-won structure lessons (R0..R8):
//  - default __launch_bounds__(256) ONLY. (256,8) -> compiler spills (373us).
//  - runtime `sym` + in-loop guards keep regs in check (R1: 108 VGPR, 2x).
//  - NO single-address atomic finalize (~65us serialized tail, R1/R4).
//  - compact balance-ordered grid + prologue-hoisted norms (R6, 79->56us).
//  - B panel in LDS, XOR-swizzle f(x)=x^(((x>>7)&7)<<4) BOTH sides (R7,
//    56->~40us, 0 bank conflicts).
//  - R8: doubling blocks/CU (16KB panel) was NEUTRAL -> occupancy is not
//    the binder; per-block overhead (stage+drain+barrier+prologue) is.
//  - R9: amortize it. Block tile 512(i)x128(j): stage B once, sweep 4
//    A-chunks of 128 rows. 2112 blocks (one resident generation), 4x fewer
//    barriers, 4x less staging traffic, 64 tiles/wave interleave.
// ---------------------------------------------------------------------------

using short8  = __attribute__((ext_vector_type(8))) short;  // 8 bf16 (4 VGPRs)
using f32x4   = __attribute__((ext_vector_type(4))) float;  // 4 fp32
using float4v = __attribute__((ext_vector_type(4))) float;

#define NROWS 8192
#define DDIM  64
// 1024 XY (dispatched first) + 2*544 sym-upper (512x128 blocks).
#define GRID_MAIN (1024 + 2 * 544)

// sqrt(log2(e)) / 8
#define PRESCALE 0.15014030109830622f

__device__ __forceinline__ float exp2_fast(float x) {
#if __has_builtin(__builtin_amdgcn_exp2f)
    return __builtin_amdgcn_exp2f(x);
#else
    return exp2f(x);
#endif
}

// ---------------------------------------------------------------------------
// Prep: normalize X, prescale, cast X/Y to bf16, compute s = 0.5*|row'|^2
// from the bf16-rounded values. 4 rows per wave, float4 loads. (R6-proven.)
// ---------------------------------------------------------------------------
__global__ __launch_bounds__(256) void mmd_prep(
    const float* __restrict__ z_seq, const float* __restrict__ pmean,
    const float* __restrict__ pstd, const float* __restrict__ z_prior,
    __hip_bfloat16* __restrict__ Xb, __hip_bfloat16* __restrict__ Yb,
    float* __restrict__ sxx, float* __restrict__ syy)
{
    const int tid  = threadIdx.x;
    const int lane = tid & 63;
    const int wid  = tid >> 6;
    const int w    = blockIdx.x * 4 + wid;       // wave id, 0..4095
    const int sub  = lane >> 4;                  // row within wave, 0..3
    const int row  = w * 4 + sub;                // 0..16383
    const int d0   = (lane & 15) * 4;            // dim offset, 0..60

    float4v v;
    __hip_bfloat16* dst;
    float* sdst;
    int r;
    if (row < NROWS) {
        r = row;
        float4v z  = *reinterpret_cast<const float4v*>(z_seq + (size_t)r * DDIM + d0);
        float4v pm = *reinterpret_cast<const float4v*>(pmean + d0);
        float4v ps = *reinterpret_cast<const float4v*>(pstd + d0);
#pragma unroll
        for (int k = 0; k < 4; ++k) v[k] = (z[k] - pm[k]) / ps[k];
        dst = Xb; sdst = sxx;
    } else {
        r = row - NROWS;
        v = *reinterpret_cast<const float4v*>(z_prior + (size_t)r * DDIM + d0);
        dst = Yb; sdst = syy;
    }

    ushort4 hb;
    float sq = 0.0f;
#pragma unroll
    for (int k = 0; k < 4; ++k) {
        __hip_bfloat16 b = __float2bfloat16(v[k] * PRESCALE);
        reinterpret_cast<__hip_bfloat16*>(&hb)[k] = b;
        float vb = __bfloat162float(b);
        sq += vb * vb;
    }
    *reinterpret_cast<ushort4*>(dst + (size_t)r * DDIM + d0) = hb;

    // reduce across the 16 lanes of this row-group (xor<16 stays in group)
#pragma unroll
    for (int off = 8; off; off >>= 1) sq += __shfl_xor(sq, off, 64);
    if ((lane & 15) == 0) sdst[r] = 0.5f * sq;
}

// ---------------------------------------------------------------------------
// Main: compact 1-D grid of ACTIVE blocks only.
// Block tile 512(i) x 128(j): B panel staged once, 4 A-chunks of 128 rows
// swept against it. 4 waves, wave tile 32(i) x 128(j) per chunk.
//   bid <  1024 : XY block, bi = bid>>6 (0..15), bj = bid&63.
//   bid >= 1024 : t = bid-1024; sym mode = t&1 (0:XX, 1:YY);
//                 u = t>>1 in [0,544): group g=bi has 4 bj's x (g+1) bi's;
//                 cum(g) = 2g(g+1); rem = u-cum; bj = 4g+rem/(g+1),
//                 bi = rem%(g+1).  (sym active blocks always have jB >= iB.)
// ---------------------------------------------------------------------------
__global__ __launch_bounds__(256) void mmd_main(
    const __hip_bfloat16* __restrict__ Xb, const __hip_bfloat16* __restrict__ Yb,
    const float* __restrict__ sxx, const float* __restrict__ syy,
    double* __restrict__ partials)
{
    __shared__ __align__(16) char Bs[16384];     // 128 cols x 128 B

    const int bid = blockIdx.x;

    int bi, bj;
    bool sym;
    const __hip_bfloat16* A;
    const __hip_bfloat16* Bp;
    const float* sa;
    const float* sb;

    if (bid < 1024) {                       // XY: heavy, uniform, FIRST
        sym = false;
        bi = bid >> 6; bj = bid & 63;
        A = Xb; Bp = Yb; sa = sxx; sb = syy;
    } else {                                // sym upper-triangle blocks
        sym = true;
        const int t = bid - 1024;
        const int u = t >> 1;
        int g = (int)((sqrtf((float)(2 * u + 1)) - 1.0f) * 0.5f);
        while (2 * (g + 1) * (g + 2) <= u) ++g;  // integer fixup of float sqrt
        while (2 * g * (g + 1) > u) --g;
        const int rem = u - 2 * g * (g + 1);     // 0 .. 4(g+1)-1
        const int q   = rem / (g + 1);           // 0..3
        bj = 4 * g + q;
        bi = rem - q * (g + 1);                  // 0..g  (jB >= iB guaranteed)
        if (t & 1) { A = Yb; Bp = Yb; sa = syy; sb = syy; }
        else       { A = Xb; Bp = Xb; sa = sxx; sb = sxx; }
    }

    const int tid  = threadIdx.x;
    const int lane = tid & 63;
    const int wid  = tid >> 6;
    const int quad = lane >> 4;
    const int l15  = lane & 15;

    const int iBlock = bi * 512;
    const int jBlock = bj * 128;

    // ---- Stage B panel -> LDS, source pre-swizzled with f(x)=x^(((x>>7)&7)<<4)
    // so a swizzled read is conflict-free.  16 chunks of 1024B, 4 per wave.
    {
        const char* gB = (const char*)Bp + (size_t)jBlock * 128;
#pragma unroll
        for (int k = 0; k < 4; ++k) {
            const int c  = wid * 4 + k;
            const int x  = c * 1024 + lane * 16;
            const int gx = x ^ (((x >> 7) & 7) << 4);
            __builtin_amdgcn_global_load_lds(
                (const __attribute__((address_space(1))) void*)(gB + gx),
                (__attribute__((address_space(3))) void*)(Bs + c * 1024),
                16, 0, 0);
        }
    }

    // A-chunk 0 wave row origin; chunk c adds c*128.
    int i0 = iBlock + wid * 32;

    // A fragments + negated row half-norms for the CURRENT chunk.
    // (Chunk 0 loads overlap the LDS staging drain; later chunks are loaded
    //  right after the previous chunk's compute releases the registers.)
    short8 af[2][2];
    f32x4  nsx[2];
#pragma unroll
    for (int mt = 0; mt < 2; ++mt) {
        const int ar = i0 + mt * 16 + l15;
#pragma unroll
        for (int ks = 0; ks < 2; ++ks)
            af[mt][ks] = *reinterpret_cast<const short8*>(
                A + (size_t)ar * DDIM + ks * 32 + quad * 8);
        f32x4 s4 = *reinterpret_cast<const f32x4*>(sa + i0 + mt * 16 + quad * 4);
        nsx[mt] = -s4;
    }

    // Hoisted negated column half-norms for this lane's 8 j-tiles.
    float nsy[8];
#pragma unroll
    for (int nt = 0; nt < 8; ++nt) nsy[nt] = -sb[jBlock + l15 + nt * 16];

    __syncthreads();   // staging complete (compiler drains vmcnt first)

    // Per-lane constant swizzle for reads: col&7 == l15&7 (col = 16nt+l15).
    const int swz   = (l15 & 7) << 4;
    const int off0  = (quad * 16) ^ swz;          // ks=0 in-col byte offset
    const int off1  = (quad * 16 + 64) ^ swz;     // ks=1 in-col byte offset
    const char* lb0 = Bs + l15 * 128;

    // 4 accumulators (one per C row) break the serial add chain.
    float ls0 = 0.0f, ls1 = 0.0f, ls2 = 0.0f, ls3 = 0.0f;

    for (int c = 0; c < 4; ++c) {
#pragma unroll
        for (int nt = 0; nt < 8; ++nt) {
            const int jt = jBlock + nt * 16;
            if (sym && jt < i0) continue;    // both mt-tiles below diagonal

            const char* lp = lb0 + nt * 16 * 128;
            short8 b0 = *reinterpret_cast<const short8*>(lp + off0);
            short8 b1 = *reinterpret_cast<const short8*>(lp + off1);

#pragma unroll
            for (int mt = 0; mt < 2; ++mt) {
                const int it = i0 + mt * 16;
                if (sym && jt < it) continue;      // tile strictly below diag

                f32x4 acc4;
#pragma unroll
                for (int r = 0; r < 4; ++r) acc4[r] = nsx[mt][r] + nsy[nt];
                acc4 = __builtin_amdgcn_mfma_f32_16x16x32_bf16(af[mt][0], b0, acc4, 0, 0, 0);
                acc4 = __builtin_amdgcn_mfma_f32_16x16x32_bf16(af[mt][1], b1, acc4, 0, 0, 0);

                if (sym && jt == it) {
                    // diagonal tile: count only j > i (trace excluded exactly)
                    ls0 += (l15 > quad * 4 + 0) ? exp2_fast(acc4[0]) : 0.0f;
                    ls1 += (l15 > quad * 4 + 1) ? exp2_fast(acc4[1]) : 0.0f;
                    ls2 += (l15 > quad * 4 + 2) ? exp2_fast(acc4[2]) : 0.0f;
                    ls3 += (l15 > quad * 4 + 3) ? exp2_fast(acc4[3]) : 0.0f;
                } else {
                    ls0 += exp2_fast(acc4[0]);
                    ls1 += exp2_fast(acc4[1]);
                    ls2 += exp2_fast(acc4[2]);
                    ls3 += exp2_fast(acc4[3]);
                }
            }
        }

        // Load next chunk's A fragments (releases af/nsx WAR after compute;
        // latency hides under the loop-around exp/adds + peer waves).
        if (c < 3) {
            const int i0n = i0 + 128;
            if (sym && jBlock + 112 < i0n) break;   // all later chunks empty
#pragma unroll
            for (int mt = 0; mt < 2; ++mt) {
                const int ar = i0n + mt * 16 + l15;
#pragma unroll
                for (int ks = 0; ks < 2; ++ks)
                    af[mt][ks] = *reinterpret_cast<const short8*>(
                        A + (size_t)ar * DDIM + ks * 32 + quad * 8);
                f32x4 s4 = *reinterpret_cast<const f32x4*>(sa + i0n + mt * 16 + quad * 4);
                nsx[mt] = -s4;
            }
            i0 = i0n;
        }
    }

    float lsum = (ls0 + ls1) + (ls2 + ls3);

    // wave reduce
#pragma unroll
    for (int off = 32; off; off >>= 1) lsum += __shfl_xor(lsum, off, 64);

    __shared__ float ws4[4];
    if (lane == 0) ws4[wid] = lsum;
    __syncthreads();
    if (tid == 0) {
        double tot = (double)ws4[0] + (double)ws4[1] + (double)ws4[2] + (double)ws4[3];
        partials[bid] = tot;
    }
}

// ---------------------------------------------------------------------------
// Finalize: reduce GRID_MAIN block partials with per-mode coefficients.
// bid < 1024 -> XY (negative coeff); else sym (x2 folds sum_{i!=j}).
// ---------------------------------------------------------------------------
__global__ __launch_bounds__(256) void mmd_final(
    const double* __restrict__ partials, float* __restrict__ out)
{
    const int tid = threadIdx.x;
    const double cs = 2.0 / (8192.0 * 8191.0);       // sym modes
    const double cx = -2.0 / (8192.0 * 8192.0);      // XY

    double s = 0.0;
    for (int idx = tid; idx < GRID_MAIN; idx += 256) {
        double c = (idx < 1024) ? cx : cs;
        s += partials[idx] * c;
    }
#pragma unroll
    for (int off = 32; off; off >>= 1) s += __shfl_xor(s, off, 64);

    __shared__ double wsum[4];
    const int lane = tid & 63, wid = tid >> 6;
    if (lane == 0) wsum[wid] = s;
    __syncthreads();
    if (tid == 0) {
        double mmd = wsum[0] + wsum[1] + wsum[2] + wsum[3];
        out[0] = (float)(mmd > 0.0 ? mmd : 0.0);
    }
}

// ---------------------------------------------------------------------------
extern "C" void kernel_launch(void* const* d_in, const int* in_sizes, int n_in,
                              void* d_out, int out_size, void* d_ws, size_t ws_size,
                              hipStream_t stream) {
    const float* z_seq   = (const float*)d_in[0];   // [16,512,64]
    const float* pmean   = (const float*)d_in[1];   // [64]
    const float* pstd    = (const float*)d_in[2];   // [64]
    const float* z_prior = (const float*)d_in[3];   // [8192,64]
    float* out = (float*)d_out;

    char* ws = (char*)d_ws;
    __hip_bfloat16* Xb = (__hip_bfloat16*)(ws);                    // 1 MB
    __hip_bfloat16* Yb = (__hip_bfloat16*)(ws + (1u << 20));       // 1 MB
    float* sxx = (float*)(ws + (2u << 20));                        // 32 KB
    float* syy = (float*)(ws + (2u << 20) + 32768);                // 32 KB
    double* partials = (double*)(ws + (2u << 20) + 65536);         // ~17 KB

    mmd_prep<<<dim3(1024), dim3(256), 0, stream>>>(
        z_seq, pmean, pstd, z_prior, Xb, Yb, sxx, syy);
    mmd_main<<<dim3(GRID_MAIN), dim3(256), 0, stream>>>(
        Xb, Yb, sxx, syy, partials);
    mmd_final<<<dim3(1), dim3(256), 0, stream>>>(partials, out);
}